// Round 6
// baseline (345.940 us; speedup 1.0000x reference)
//
#include <hip/hip_runtime.h>
#include <cstddef>

// Problem constants
#define NB 16
#define NVOX 128
#define NPT 1920
#define NPAIRS 32768   // 16 b * 16 tz * 16 ty * 8 x-pairs

static __device__ __forceinline__ float2 f2(float a, float b) {
    float2 r; r.x = a; r.y = b; return r;
}

// ---------------------------------------------------------------------------
// Stage 1: Conv1d(256,240,1) on the (256,8) view, all 16 batches.
// One block per output channel o (240 blocks), split-K over 2 halves.
// ---------------------------------------------------------------------------
__global__ __launch_bounds__(256)
void mlp_stage1(const float* __restrict__ q, const float* __restrict__ w1,
                const float* __restrict__ b1, float* __restrict__ x1g)
{
    __shared__ float wrow[256];
    __shared__ float psum[256];
    const int o = blockIdx.x;
    const int t = threadIdx.x;

    wrow[t] = w1[o * 256 + t];
    __syncthreads();

    const int half = t >> 7;
    const int bl = t & 127;
    const int b = bl >> 3, l = bl & 7;
    const float* qb = q + b * 2048 + l + half * 1024;
    float s = 0.f;
    #pragma unroll 8
    for (int i = 0; i < 128; ++i)
        s = fmaf(wrow[half * 128 + i], qb[i * 8], s);
    psum[t] = s;
    __syncthreads();

    if (t < 128) {
        int bb = t >> 3, ll = t & 7;
        x1g[bb * 1920 + o * 8 + ll] = b1[o] + psum[t] + psum[t + 128];
    }
}

// ---------------------------------------------------------------------------
// Helper: bin ranges for a point (pair units in x, tile units in y/z).
// Output span per axis: [c0-3, c0+4] clamped to [0,127].
// ---------------------------------------------------------------------------
__device__ __forceinline__ void bin_range(int x0, int y0, int z0,
                                          int& pxl, int& pxh, int& tyl, int& tyh,
                                          int& tzl, int& tzh)
{
    pxl = max(0, x0 - 3) >> 4; pxh = min(127, x0 + 4) >> 4;
    tyl = max(0, y0 - 3) >> 3; tyh = min(127, y0 + 4) >> 3;
    tzl = max(0, z0 - 3) >> 3; tzh = min(127, z0 + 4) >> 3;
}

// ---------------------------------------------------------------------------
// Tail: IN chains + grouped convs + point generation + per-pair counts.
// One block per batch, 256 threads.
// ---------------------------------------------------------------------------
__global__ __launch_bounds__(256)
void mlp_tail(const float* __restrict__ x1g, const float* __restrict__ qval,
              const float* __restrict__ w2, const float* __restrict__ b2,
              const float* __restrict__ w3, const float* __restrict__ b3,
              const float* __restrict__ w4, const float* __restrict__ b4,
              const float* __restrict__ w5, const float* __restrict__ b5,
              float4* __restrict__ pts, int* __restrict__ counts)
{
    __shared__ float bufA[7680];
    __shared__ float bufC[3840];
    __shared__ float psum[256], psq[256];
    __shared__ float meanv[64], rstdv[64];
    __shared__ float m4[16], r4[16];

    const int b = blockIdx.x;
    const int t = threadIdx.x;

    for (int u = t; u < 1920; u += 256) bufA[u] = x1g[b * 1920 + u];
    __syncthreads();

    // IN1 over (64,30)
    {
        int c = t >> 2, g = t & 3;
        float s = 0.f, s2 = 0.f;
        for (int p = g; p < 30; p += 4) { float v = bufA[c * 30 + p]; s += v; s2 += v * v; }
        psum[t] = s; psq[t] = s2;
    }
    __syncthreads();
    if (t < 64) {
        float s = 0.f, s2 = 0.f;
        for (int g = 0; g < 4; ++g) { s += psum[t * 4 + g]; s2 += psq[t * 4 + g]; }
        float m = s * (1.f / 30.f);
        float var = s2 * (1.f / 30.f) - m * m;
        meanv[t] = m; rstdv[t] = rsqrtf(var + 1e-5f);
    }
    __syncthreads();
    for (int k = t; k < 1920; k += 256) {
        int c = k / 30;
        bufA[k] = fmaxf((bufA[k] - meanv[c]) * rstdv[c], 0.f);
    }
    __syncthreads();

    // stage2: grouped conv 64->128, flat (32,120)
    for (int m = t; m < 3840; m += 256) {
        int c = m / 60;
        int r = m - c * 60;
        int j = r / 30;
        int p = r - j * 30;
        bufC[m] = fmaf(bufA[c * 30 + p], w2[c * 2 + j], b2[c * 2 + j]);
    }
    __syncthreads();
    // IN2 over (32,120)
    {
        int c = t >> 3, g = t & 7;
        float s = 0.f, s2 = 0.f;
        for (int p = g; p < 120; p += 8) { float v = bufC[c * 120 + p]; s += v; s2 += v * v; }
        psum[t] = s; psq[t] = s2;
    }
    __syncthreads();
    if (t < 32) {
        float s = 0.f, s2 = 0.f;
        for (int g = 0; g < 8; ++g) { s += psum[t * 8 + g]; s2 += psq[t * 8 + g]; }
        float m = s * (1.f / 120.f);
        float var = s2 * (1.f / 120.f) - m * m;
        meanv[t] = m; rstdv[t] = rsqrtf(var + 1e-5f);
    }
    __syncthreads();
    for (int m = t; m < 3840; m += 256) {
        int c = m / 120;
        bufC[m] = fmaxf((bufC[m] - meanv[c]) * rstdv[c], 0.f);
    }
    __syncthreads();

    // stage3: grouped conv 32->64, flat (16,480)
    for (int m = t; m < 7680; m += 256) {
        int c = m / 240;
        int r = m - c * 240;
        int j = r / 120;
        int p = r - j * 120;
        bufA[m] = fmaf(bufC[c * 120 + p], w3[c * 2 + j], b3[c * 2 + j]);
    }
    __syncthreads();

    // IN3 over (16,480): 16 threads/channel
    const int c3 = t >> 4, g3 = t & 15;
    {
        float s = 0.f, s2 = 0.f;
        for (int k = 0; k < 30; ++k) { float v = bufA[c3 * 480 + g3 + 16 * k]; s += v; s2 += v * v; }
        psum[t] = s; psq[t] = s2;
    }
    __syncthreads();
    if (t < 16) {
        float s = 0.f, s2 = 0.f;
        for (int g = 0; g < 16; ++g) { s += psum[t * 16 + g]; s2 += psq[t * 16 + g]; }
        float m = s * (1.f / 480.f);
        float var = s2 * (1.f / 480.f) - m * m;
        meanv[t] = m; rstdv[t] = rsqrtf(var + 1e-5f);
    }
    __syncthreads();
    {
        float m = meanv[c3], r = rstdv[c3];
        float s = 0.f, s2 = 0.f;
        for (int k = 0; k < 30; ++k) {
            int idx = c3 * 480 + g3 + 16 * k;
            float v = fmaxf((bufA[idx] - m) * r, 0.f);
            bufA[idx] = v; s += v; s2 += v * v;
        }
        psum[t] = s; psq[t] = s2;
    }
    __syncthreads();
    // stage4 IN stats analytically
    if (t < 16) {
        float s = 0.f, s2 = 0.f;
        for (int g = 0; g < 16; ++g) { s += psum[t * 16 + g]; s2 += psq[t * 16 + g]; }
        float sum4 = 0.f, sq4 = 0.f;
        for (int j = 0; j < 4; ++j) {
            float w = w4[t * 4 + j], bb = b4[t * 4 + j];
            sum4 += w * s + 480.f * bb;
            sq4  += w * w * s2 + 2.f * w * bb * s + 480.f * bb * bb;
        }
        float m = sum4 * (1.f / 1920.f);
        float var = sq4 * (1.f / 1920.f) - m * m;
        m4[t] = m; r4[t] = rsqrtf(var + 1e-5f);
    }
    __syncthreads();

    // per-point: stage4 apply + stage5 + tanh + emit point + count bins
    for (int l = t; l < NPT; l += 256) {
        int j = l / 480;
        int p = l - j * 480;
        float a0 = b5[0], a1 = b5[1], a2 = b5[2];
        #pragma unroll
        for (int c = 0; c < 16; ++c) {
            float xv = bufA[c * 480 + p];
            float x4 = fmaf(xv, w4[c * 4 + j], b4[c * 4 + j]);
            float h  = fmaxf((x4 - m4[c]) * r4[c], 0.f);
            a0 = fmaf(w5[c],      h, a0);
            a1 = fmaf(w5[16 + c], h, a1);
            a2 = fmaf(w5[32 + c], h, a2);
        }
        float px = tanhf(a0) * 64.f + 63.5f;
        float py = tanhf(a1) * 64.f + 63.5f;
        float pz = tanhf(a2) * 64.f + 63.5f;
        float val = 1.f / (1.f + expf(-qval[l]));

        float4 pv; pv.x = px; pv.y = py; pv.z = pz; pv.w = val;
        pts[b * NPT + l] = pv;

        int x0 = (int)floorf(px), y0 = (int)floorf(py), z0 = (int)floorf(pz);
        int pxl, pxh, tyl, tyh, tzl, tzh;
        bin_range(x0, y0, z0, pxl, pxh, tyl, tyh, tzl, tzh);
        for (int tz = tzl; tz <= tzh; ++tz)
            for (int ty = tyl; ty <= tyh; ++ty)
                for (int px_ = pxl; px_ <= pxh; ++px_)
                    atomicAdd(&counts[((b * 16 + tz) * 16 + ty) * 8 + px_], 1);
    }
}

// ---------------------------------------------------------------------------
// Exclusive scan of 32768 counts -> offsets (32769) and cursors copy.
// Single block, 1024 threads, 32 values each.
// ---------------------------------------------------------------------------
__global__ __launch_bounds__(1024)
void scan32k(const int* __restrict__ counts, int* __restrict__ offsets,
             int* __restrict__ cursors)
{
    __shared__ int part[1024];
    const int t = threadIdx.x;
    int s = 0;
    int local[32];
    #pragma unroll
    for (int i = 0; i < 32; ++i) { local[i] = counts[t * 32 + i]; s += local[i]; }
    part[t] = s;
    __syncthreads();
    for (int off = 1; off < 1024; off <<= 1) {
        int v = (t >= off) ? part[t - off] : 0;
        __syncthreads();
        part[t] += v;
        __syncthreads();
    }
    int running = part[t] - s;   // exclusive prefix of this thread's chunk
    #pragma unroll
    for (int i = 0; i < 32; ++i) {
        offsets[t * 32 + i] = running;
        cursors[t * 32 + i] = running;
        running += local[i];
    }
    if (t == 1023) offsets[32768] = running;
}

// ---------------------------------------------------------------------------
// Scatter points into per-pair bins.
// ---------------------------------------------------------------------------
__global__ __launch_bounds__(256)
void bin_fill(const float4* __restrict__ pts, int* __restrict__ cursors,
              float4* __restrict__ binned)
{
    int i = blockIdx.x * 256 + threadIdx.x;   // 0 .. 30719
    int b = i / NPT;
    float4 pt = pts[i];
    int x0 = (int)floorf(pt.x), y0 = (int)floorf(pt.y), z0 = (int)floorf(pt.z);
    int pxl, pxh, tyl, tyh, tzl, tzh;
    bin_range(x0, y0, z0, pxl, pxh, tyl, tyh, tzl, tzh);
    for (int tz = tzl; tz <= tzh; ++tz)
        for (int ty = tyl; ty <= tyh; ++ty)
            for (int px_ = pxl; px_ <= pxh; ++px_) {
                int bin = ((b * 16 + tz) * 16 + ty) * 8 + px_;
                int pos = atomicAdd(&cursors[bin], 1);
                binned[pos] = pt;
            }
}

// ---------------------------------------------------------------------------
// Per-axis composed 7-tap coefficients (A^3, zero-padded 3-tap average).
// ---------------------------------------------------------------------------
__device__ __forceinline__ void coef(int g, float& cm1, float& c0, float& cp1)
{
    cm1 = (g == 1 || g == 127) ? 5.f : 6.f;
    c0  = (g == 0 || g == 127) ? 4.f : 7.f;
    cp1 = (g == 0 || g == 126) ? 5.f : 6.f;
}

// ---------------------------------------------------------------------------
// Tile kernel: one block per 16x8x8 output region. n==0 -> zero-fill & exit.
// Active: splat binned points into 22x14x14 LDS tile (raw[z14][y14][x22]),
// then in-place register-column z/y passes and row-wise x-pass + divide.
// LDS = 34.5 KB -> 4 blocks/CU.
// ---------------------------------------------------------------------------
__global__ __launch_bounds__(256)
void tile_smooth(const float4* __restrict__ binned,
                 const int* __restrict__ offsets, float* __restrict__ out)
{
    __shared__ __align__(16) float2 raw[14 * 14 * 22];   // 34496 B

    const int code = blockIdx.x;
    const int pair = code & 7;
    const int ty   = (code >> 3) & 15;
    const int tz   = (code >> 7) & 15;
    const int b    = code >> 11;
    const int Tx = pair * 16, Ty = ty * 8, Tz = tz * 8;
    const int t = threadIdx.x;

    const int off = offsets[code];
    const int n   = offsets[code + 1] - off;

    float* ob = out + (((size_t)(b * NVOX + Tz) * NVOX + Ty) * NVOX + Tx);

    if (n == 0) {
        // zero 16x8x8 region: 256 float4 stores
        int z = t >> 5, y = (t >> 2) & 7, qx = t & 3;
        *(float4*)(ob + ((size_t)z * NVOX + y) * NVOX + qx * 4) =
            make_float4(0.f, 0.f, 0.f, 0.f);
        return;
    }

    // zero raw
    {
        float4* r4p = (float4*)raw;
        for (int u = t; u < 14 * 14 * 11; u += 256)
            r4p[u] = make_float4(0.f, 0.f, 0.f, 0.f);
    }
    __syncthreads();

    // splat this pair's points
    for (int p = t; p < n; p += 256) {
        float4 pt = binned[off + p];
        float x0f = floorf(pt.x), y0f = floorf(pt.y), z0f = floorf(pt.z);
        int x0 = (int)x0f, y0 = (int)y0f, z0 = (int)z0f;
        int lx0 = x0 - Tx + 3, ly0 = y0 - Ty + 3, lz0 = z0 - Tz + 3;
        float fx = pt.x - x0f, fy = pt.y - y0f, fz = pt.z - z0f;
        float val = pt.w;
        #pragma unroll
        for (int dz = 0; dz < 2; ++dz) {
            int zi = z0 + dz, lz = lz0 + dz;
            if ((unsigned)zi >= 128u || (unsigned)lz >= 14u) continue;
            float wz = dz ? fz : 1.f - fz;
            #pragma unroll
            for (int dy = 0; dy < 2; ++dy) {
                int yi = y0 + dy, ly = ly0 + dy;
                if ((unsigned)yi >= 128u || (unsigned)ly >= 14u) continue;
                float wy = dy ? fy : 1.f - fy;
                #pragma unroll
                for (int dx = 0; dx < 2; ++dx) {
                    int xi = x0 + dx, lx = lx0 + dx;
                    if ((unsigned)xi >= 128u || (unsigned)lx >= 22u) continue;
                    float w = (dx ? fx : 1.f - fx) * wy * wz;
                    float2* cell = &raw[(lz * 14 + ly) * 22 + lx];
                    atomicAdd(&cell->x, w * val);
                    atomicAdd(&cell->y, w);
                }
            }
        }
    }
    __syncthreads();

    // z-pass (in place): thread owns column (ly,lx); reads z=0..13 into regs,
    // writes 8 outputs to z rows 3..10 of the SAME column (no cross-thread hazard).
    for (int cc = t; cc < 14 * 22; cc += 256) {
        int ly = cc / 22, lx = cc - ly * 22;
        float2 v[14];
        #pragma unroll
        for (int j = 0; j < 14; ++j) v[j] = raw[(j * 14 + ly) * 22 + lx];
        #pragma unroll
        for (int k = 0; k < 8; ++k) {
            float cm1, c0, cp1; coef(Tz + k, cm1, c0, cp1);
            float sx = (v[k].x + v[k + 6].x) + 3.f * (v[k + 1].x + v[k + 5].x)
                     + cm1 * v[k + 2].x + c0 * v[k + 3].x + cp1 * v[k + 4].x;
            float sy = (v[k].y + v[k + 6].y) + 3.f * (v[k + 1].y + v[k + 5].y)
                     + cm1 * v[k + 2].y + c0 * v[k + 3].y + cp1 * v[k + 4].y;
            raw[((k + 3) * 14 + ly) * 22 + lx] = f2(sx * (1.f / 27.f), sy * (1.f / 27.f));
        }
    }
    __syncthreads();

    // y-pass (in place): thread owns column (lz,lx), z rows 3..10.
    if (t < 8 * 22) {
        int lz = t / 22, lx = t - lz * 22;
        float2 v[14];
        #pragma unroll
        for (int j = 0; j < 14; ++j) v[j] = raw[((lz + 3) * 14 + j) * 22 + lx];
        #pragma unroll
        for (int k = 0; k < 8; ++k) {
            float cm1, c0, cp1; coef(Ty + k, cm1, c0, cp1);
            float sx = (v[k].x + v[k + 6].x) + 3.f * (v[k + 1].x + v[k + 5].x)
                     + cm1 * v[k + 2].x + c0 * v[k + 3].x + cp1 * v[k + 4].x;
            float sy = (v[k].y + v[k + 6].y) + 3.f * (v[k + 1].y + v[k + 5].y)
                     + cm1 * v[k + 2].y + c0 * v[k + 3].y + cp1 * v[k + 4].y;
            raw[((lz + 3) * 14 + (k + 3)) * 22 + lx] = f2(sx * (1.f / 27.f), sy * (1.f / 27.f));
        }
    }
    __syncthreads();

    // x-pass + division: 4 threads per (z,y) row, 4 outputs each, float4 store.
    {
        int row = t >> 2, qx = t & 3;
        int z = row >> 3, y = row & 7;
        const float2* base = &raw[((z + 3) * 14 + (y + 3)) * 22];
        float2 m[10];
        #pragma unroll
        for (int j = 0; j < 10; ++j) m[j] = base[4 * qx + j];
        float4 res;
        float* rp = (float*)&res;
        #pragma unroll
        for (int xi = 0; xi < 4; ++xi) {
            int gx = Tx + 4 * qx + xi;
            float cm1, c0, cp1; coef(gx, cm1, c0, cp1);
            float sx = (m[xi].x + m[xi + 6].x) + 3.f * (m[xi + 1].x + m[xi + 5].x)
                     + cm1 * m[xi + 2].x + c0 * m[xi + 3].x + cp1 * m[xi + 4].x;
            float sy = (m[xi].y + m[xi + 6].y) + 3.f * (m[xi + 1].y + m[xi + 5].y)
                     + cm1 * m[xi + 2].y + c0 * m[xi + 3].y + cp1 * m[xi + 4].y;
            rp[xi] = (sx * (1.f / 27.f)) / (sy * (1.f / 27.f) + 0.001f);
        }
        *(float4*)(ob + ((size_t)z * NVOX + y) * NVOX + qx * 4) = res;
    }
}

// ---------------------------------------------------------------------------
extern "C" void kernel_launch(void* const* d_in, const int* in_sizes, int n_in,
                              void* d_out, int out_size, void* d_ws, size_t ws_size,
                              hipStream_t stream)
{
    const float* q    = (const float*)d_in[0];
    const float* qval = (const float*)d_in[1];
    const float* w1   = (const float*)d_in[2];
    const float* b1   = (const float*)d_in[3];
    const float* w2   = (const float*)d_in[4];
    const float* b2   = (const float*)d_in[5];
    const float* w3   = (const float*)d_in[6];
    const float* b3   = (const float*)d_in[7];
    const float* w4   = (const float*)d_in[8];
    const float* b4   = (const float*)d_in[9];
    const float* w5   = (const float*)d_in[10];
    const float* b5   = (const float*)d_in[11];
    float* out = (float*)d_out;

    // ws layout (bytes):
    //   counts  @ 0x000000  (32768 int = 128 KB)
    //   offsets @ 0x040000  (32769 int)
    //   cursors @ 0x080000  (32768 int)
    //   pts     @ 0x0C0000  (30720 float4 = 480 KB)
    //   binned  @ 0x140000  (<=245760 float4 = 3.75 MB)
    //   x1g     @ 0x600000  (30720 float)
    int*    counts  = (int*)d_ws;
    int*    offsets = (int*)((char*)d_ws + 0x040000);
    int*    cursors = (int*)((char*)d_ws + 0x080000);
    float4* pts     = (float4*)((char*)d_ws + 0x0C0000);
    float4* binned  = (float4*)((char*)d_ws + 0x140000);
    float*  x1g     = (float*)((char*)d_ws + 0x600000);

    hipMemsetAsync(counts, 0, 32768 * sizeof(int), stream);

    mlp_stage1<<<240, 256, 0, stream>>>(q, w1, b1, x1g);

    mlp_tail<<<NB, 256, 0, stream>>>(x1g, qval, w2, b2, w3, b3,
                                     w4, b4, w5, b5, pts, counts);

    scan32k<<<1, 1024, 0, stream>>>(counts, offsets, cursors);

    bin_fill<<<(NB * NPT) / 256, 256, 0, stream>>>(pts, cursors, binned);

    tile_smooth<<<NPAIRS, 256, 0, stream>>>(binned, offsets, out);
}

// Round 7
// 256.985 us; speedup vs baseline: 1.3461x; 1.3461x over previous
//
#include <hip/hip_runtime.h>
#include <cstddef>

// Problem constants
#define NB 16
#define NVOX 128
#define NPT 1920
#define NBINS 32768    // 16 b * 16 tz * 16 ty * 8 x-pairs (per-batch 2048)

static __device__ __forceinline__ float2 f2(float a, float b) {
    float2 r; r.x = a; r.y = b; return r;
}

// ---------------------------------------------------------------------------
// Zero the whole output at full write BW. 4096 blocks x 256 thr x 8 float4.
// ---------------------------------------------------------------------------
__global__ __launch_bounds__(256)
void zero_out(float4* __restrict__ out)
{
    int idx = blockIdx.x * 2048 + threadIdx.x;
    #pragma unroll
    for (int i = 0; i < 8; ++i)
        out[idx + i * 256] = make_float4(0.f, 0.f, 0.f, 0.f);
}

// ---------------------------------------------------------------------------
// Stage 1: Conv1d(256,240,1) on the (256,8) view, all 16 batches.
// ---------------------------------------------------------------------------
__global__ __launch_bounds__(256)
void mlp_stage1(const float* __restrict__ q, const float* __restrict__ w1,
                const float* __restrict__ b1, float* __restrict__ x1g)
{
    __shared__ float wrow[256];
    __shared__ float psum[256];
    const int o = blockIdx.x;
    const int t = threadIdx.x;

    wrow[t] = w1[o * 256 + t];
    __syncthreads();

    const int half = t >> 7;
    const int bl = t & 127;
    const int b = bl >> 3, l = bl & 7;
    const float* qb = q + b * 2048 + l + half * 1024;
    float s = 0.f;
    #pragma unroll 8
    for (int i = 0; i < 128; ++i)
        s = fmaf(wrow[half * 128 + i], qb[i * 8], s);
    psum[t] = s;
    __syncthreads();

    if (t < 128) {
        int bb = t >> 3, ll = t & 7;
        x1g[bb * 1920 + o * 8 + ll] = b1[o] + psum[t] + psum[t + 128];
    }
}

// ---------------------------------------------------------------------------
// Bin range helper (pair units in x, tile units in y/z); span [c0-3, c0+4].
// ---------------------------------------------------------------------------
__device__ __forceinline__ void bin_range(int x0, int y0, int z0,
                                          int& pxl, int& pxh, int& tyl, int& tyh,
                                          int& tzl, int& tzh)
{
    pxl = max(0, x0 - 3) >> 4; pxh = min(127, x0 + 4) >> 4;
    tyl = max(0, y0 - 3) >> 3; tyh = min(127, y0 + 4) >> 3;
    tzl = max(0, z0 - 3) >> 3; tzh = min(127, z0 + 4) >> 3;
}

// ---------------------------------------------------------------------------
// Tail: IN chains + grouped convs + point generation (no global atomics).
// ---------------------------------------------------------------------------
__global__ __launch_bounds__(256)
void mlp_tail(const float* __restrict__ x1g, const float* __restrict__ qval,
              const float* __restrict__ w2, const float* __restrict__ b2,
              const float* __restrict__ w3, const float* __restrict__ b3,
              const float* __restrict__ w4, const float* __restrict__ b4,
              const float* __restrict__ w5, const float* __restrict__ b5,
              float4* __restrict__ pts)
{
    __shared__ float bufA[7680];
    __shared__ float bufC[3840];
    __shared__ float psum[256], psq[256];
    __shared__ float meanv[64], rstdv[64];
    __shared__ float m4[16], r4[16];

    const int b = blockIdx.x;
    const int t = threadIdx.x;

    for (int u = t; u < 1920; u += 256) bufA[u] = x1g[b * 1920 + u];
    __syncthreads();

    // IN1 over (64,30)
    {
        int c = t >> 2, g = t & 3;
        float s = 0.f, s2 = 0.f;
        for (int p = g; p < 30; p += 4) { float v = bufA[c * 30 + p]; s += v; s2 += v * v; }
        psum[t] = s; psq[t] = s2;
    }
    __syncthreads();
    if (t < 64) {
        float s = 0.f, s2 = 0.f;
        for (int g = 0; g < 4; ++g) { s += psum[t * 4 + g]; s2 += psq[t * 4 + g]; }
        float m = s * (1.f / 30.f);
        float var = s2 * (1.f / 30.f) - m * m;
        meanv[t] = m; rstdv[t] = rsqrtf(var + 1e-5f);
    }
    __syncthreads();
    for (int k = t; k < 1920; k += 256) {
        int c = k / 30;
        bufA[k] = fmaxf((bufA[k] - meanv[c]) * rstdv[c], 0.f);
    }
    __syncthreads();

    // stage2: grouped conv 64->128, flat (32,120)
    for (int m = t; m < 3840; m += 256) {
        int c = m / 60;
        int r = m - c * 60;
        int j = r / 30;
        int p = r - j * 30;
        bufC[m] = fmaf(bufA[c * 30 + p], w2[c * 2 + j], b2[c * 2 + j]);
    }
    __syncthreads();
    // IN2 over (32,120)
    {
        int c = t >> 3, g = t & 7;
        float s = 0.f, s2 = 0.f;
        for (int p = g; p < 120; p += 8) { float v = bufC[c * 120 + p]; s += v; s2 += v * v; }
        psum[t] = s; psq[t] = s2;
    }
    __syncthreads();
    if (t < 32) {
        float s = 0.f, s2 = 0.f;
        for (int g = 0; g < 8; ++g) { s += psum[t * 8 + g]; s2 += psq[t * 8 + g]; }
        float m = s * (1.f / 120.f);
        float var = s2 * (1.f / 120.f) - m * m;
        meanv[t] = m; rstdv[t] = rsqrtf(var + 1e-5f);
    }
    __syncthreads();
    for (int m = t; m < 3840; m += 256) {
        int c = m / 120;
        bufC[m] = fmaxf((bufC[m] - meanv[c]) * rstdv[c], 0.f);
    }
    __syncthreads();

    // stage3: grouped conv 32->64, flat (16,480)
    for (int m = t; m < 7680; m += 256) {
        int c = m / 240;
        int r = m - c * 240;
        int j = r / 120;
        int p = r - j * 120;
        bufA[m] = fmaf(bufC[c * 120 + p], w3[c * 2 + j], b3[c * 2 + j]);
    }
    __syncthreads();

    // IN3 over (16,480): 16 threads/channel
    const int c3 = t >> 4, g3 = t & 15;
    {
        float s = 0.f, s2 = 0.f;
        for (int k = 0; k < 30; ++k) { float v = bufA[c3 * 480 + g3 + 16 * k]; s += v; s2 += v * v; }
        psum[t] = s; psq[t] = s2;
    }
    __syncthreads();
    if (t < 16) {
        float s = 0.f, s2 = 0.f;
        for (int g = 0; g < 16; ++g) { s += psum[t * 16 + g]; s2 += psq[t * 16 + g]; }
        float m = s * (1.f / 480.f);
        float var = s2 * (1.f / 480.f) - m * m;
        meanv[t] = m; rstdv[t] = rsqrtf(var + 1e-5f);
    }
    __syncthreads();
    {
        float m = meanv[c3], r = rstdv[c3];
        float s = 0.f, s2 = 0.f;
        for (int k = 0; k < 30; ++k) {
            int idx = c3 * 480 + g3 + 16 * k;
            float v = fmaxf((bufA[idx] - m) * r, 0.f);
            bufA[idx] = v; s += v; s2 += v * v;
        }
        psum[t] = s; psq[t] = s2;
    }
    __syncthreads();
    // stage4 IN stats analytically
    if (t < 16) {
        float s = 0.f, s2 = 0.f;
        for (int g = 0; g < 16; ++g) { s += psum[t * 16 + g]; s2 += psq[t * 16 + g]; }
        float sum4 = 0.f, sq4 = 0.f;
        for (int j = 0; j < 4; ++j) {
            float w = w4[t * 4 + j], bb = b4[t * 4 + j];
            sum4 += w * s + 480.f * bb;
            sq4  += w * w * s2 + 2.f * w * bb * s + 480.f * bb * bb;
        }
        float m = sum4 * (1.f / 1920.f);
        float var = sq4 * (1.f / 1920.f) - m * m;
        m4[t] = m; r4[t] = rsqrtf(var + 1e-5f);
    }
    __syncthreads();

    // per-point: stage4 apply + stage5 + tanh + emit point
    for (int l = t; l < NPT; l += 256) {
        int j = l / 480;
        int p = l - j * 480;
        float a0 = b5[0], a1 = b5[1], a2 = b5[2];
        #pragma unroll
        for (int c = 0; c < 16; ++c) {
            float xv = bufA[c * 480 + p];
            float x4 = fmaf(xv, w4[c * 4 + j], b4[c * 4 + j]);
            float h  = fmaxf((x4 - m4[c]) * r4[c], 0.f);
            a0 = fmaf(w5[c],      h, a0);
            a1 = fmaf(w5[16 + c], h, a1);
            a2 = fmaf(w5[32 + c], h, a2);
        }
        float px = tanhf(a0) * 64.f + 63.5f;
        float py = tanhf(a1) * 64.f + 63.5f;
        float pz = tanhf(a2) * 64.f + 63.5f;
        float val = 1.f / (1.f + expf(-qval[l]));
        float4 pv; pv.x = px; pv.y = py; pv.z = pz; pv.w = val;
        pts[b * NPT + l] = pv;
    }
}

// ---------------------------------------------------------------------------
// Count per-pair incidences using an LDS histogram (one block per batch).
// ---------------------------------------------------------------------------
__global__ __launch_bounds__(256)
void count_bins(const float4* __restrict__ pts, int* __restrict__ counts)
{
    __shared__ int hist[2048];
    const int b = blockIdx.x;
    const int t = threadIdx.x;
    for (int u = t; u < 2048; u += 256) hist[u] = 0;
    __syncthreads();

    for (int l = t; l < NPT; l += 256) {
        float4 pt = pts[b * NPT + l];
        int x0 = (int)floorf(pt.x), y0 = (int)floorf(pt.y), z0 = (int)floorf(pt.z);
        int pxl, pxh, tyl, tyh, tzl, tzh;
        bin_range(x0, y0, z0, pxl, pxh, tyl, tyh, tzl, tzh);
        for (int tz = tzl; tz <= tzh; ++tz)
            for (int ty = tyl; ty <= tyh; ++ty)
                for (int px_ = pxl; px_ <= pxh; ++px_)
                    atomicAdd(&hist[(tz * 16 + ty) * 8 + px_], 1);
    }
    __syncthreads();
    for (int u = t; u < 2048; u += 256) counts[b * 2048 + u] = hist[u];
}

// ---------------------------------------------------------------------------
// Hierarchical exclusive scan of 32768 counts (coalesced).
// ---------------------------------------------------------------------------
__global__ __launch_bounds__(256)
void scan_a(const int* __restrict__ counts, int* __restrict__ offsets,
            int* __restrict__ part)
{
    __shared__ int sd[256];
    const int t = threadIdx.x;
    const int g = blockIdx.x * 256 + t;
    int v = counts[g];
    sd[t] = v;
    __syncthreads();
    for (int off = 1; off < 256; off <<= 1) {
        int u = (t >= off) ? sd[t - off] : 0;
        __syncthreads();
        sd[t] += u;
        __syncthreads();
    }
    offsets[g] = sd[t] - v;
    if (t == 255) part[blockIdx.x] = sd[t];
}

__global__ __launch_bounds__(128)
void scan_b(int* __restrict__ part, int* __restrict__ partoff,
            int* __restrict__ offsets)
{
    __shared__ int sd[128];
    const int t = threadIdx.x;
    int v = part[t];
    sd[t] = v;
    __syncthreads();
    for (int off = 1; off < 128; off <<= 1) {
        int u = (t >= off) ? sd[t - off] : 0;
        __syncthreads();
        sd[t] += u;
        __syncthreads();
    }
    partoff[t] = sd[t] - v;
    if (t == 127) offsets[NBINS] = sd[t];
}

__global__ __launch_bounds__(256)
void scan_c(int* __restrict__ offsets, const int* __restrict__ partoff,
            const int* __restrict__ counts, int* __restrict__ active,
            int* __restrict__ nact)
{
    const int g = blockIdx.x * 256 + threadIdx.x;
    offsets[g] += partoff[blockIdx.x];
    if (counts[g] != 0) {
        int p = atomicAdd(nact, 1);
        active[p] = g;
    }
}

// ---------------------------------------------------------------------------
// Scatter points into bins; cursors kept in LDS (one block per batch).
// ---------------------------------------------------------------------------
__global__ __launch_bounds__(256)
void bin_fill(const float4* __restrict__ pts, const int* __restrict__ offsets,
              float4* __restrict__ binned)
{
    __shared__ int cur[2048];
    const int b = blockIdx.x;
    const int t = threadIdx.x;
    for (int u = t; u < 2048; u += 256) cur[u] = offsets[b * 2048 + u];
    __syncthreads();

    for (int l = t; l < NPT; l += 256) {
        float4 pt = pts[b * NPT + l];
        int x0 = (int)floorf(pt.x), y0 = (int)floorf(pt.y), z0 = (int)floorf(pt.z);
        int pxl, pxh, tyl, tyh, tzl, tzh;
        bin_range(x0, y0, z0, pxl, pxh, tyl, tyh, tzl, tzh);
        for (int tz = tzl; tz <= tzh; ++tz)
            for (int ty = tyl; ty <= tyh; ++ty)
                for (int px_ = pxl; px_ <= pxh; ++px_) {
                    int pos = atomicAdd(&cur[(tz * 16 + ty) * 8 + px_], 1);
                    binned[pos] = pt;
                }
    }
}

// ---------------------------------------------------------------------------
// Per-axis composed 7-tap coefficients (A^3, zero-padded 3-tap average).
// ---------------------------------------------------------------------------
__device__ __forceinline__ void coef(int g, float& cm1, float& c0, float& cp1)
{
    cm1 = (g == 1 || g == 127) ? 5.f : 6.f;
    c0  = (g == 0 || g == 127) ? 4.f : 7.f;
    cp1 = (g == 0 || g == 126) ? 5.f : 6.f;
}

// ---------------------------------------------------------------------------
// Persistent active-tile kernel: grid 1024 (4 blocks/CU at 34.5 KB LDS);
// blocks stride over the compacted active list. Per tile: splat binned
// points into 22x14x14 LDS, in-place z/y passes, x-pass + divide, store.
// ---------------------------------------------------------------------------
__global__ __launch_bounds__(256)
void tile_active(const float4* __restrict__ binned,
                 const int* __restrict__ offsets,
                 const int* __restrict__ active,
                 const int* __restrict__ nact,
                 float* __restrict__ out)
{
    __shared__ __align__(16) float2 raw[14 * 14 * 22];   // 34496 B
    const int t = threadIdx.x;
    const int NA = *nact;

    for (int w = blockIdx.x; w < NA; w += gridDim.x) {
        const int code = active[w];
        const int pair = code & 7;
        const int ty   = (code >> 3) & 15;
        const int tz   = (code >> 7) & 15;
        const int b    = code >> 11;
        const int Tx = pair * 16, Ty = ty * 8, Tz = tz * 8;
        const int off = offsets[code];
        const int n   = offsets[code + 1] - off;
        float* ob = out + (((size_t)(b * NVOX + Tz) * NVOX + Ty) * NVOX + Tx);

        // zero raw
        {
            float4* r4p = (float4*)raw;
            for (int u = t; u < 14 * 14 * 11; u += 256)
                r4p[u] = make_float4(0.f, 0.f, 0.f, 0.f);
        }
        __syncthreads();

        // splat this pair's points
        for (int p = t; p < n; p += 256) {
            float4 pt = binned[off + p];
            float x0f = floorf(pt.x), y0f = floorf(pt.y), z0f = floorf(pt.z);
            int x0 = (int)x0f, y0 = (int)y0f, z0 = (int)z0f;
            int lx0 = x0 - Tx + 3, ly0 = y0 - Ty + 3, lz0 = z0 - Tz + 3;
            float fx = pt.x - x0f, fy = pt.y - y0f, fz = pt.z - z0f;
            float val = pt.w;
            #pragma unroll
            for (int dz = 0; dz < 2; ++dz) {
                int zi = z0 + dz, lz = lz0 + dz;
                if ((unsigned)zi >= 128u || (unsigned)lz >= 14u) continue;
                float wz = dz ? fz : 1.f - fz;
                #pragma unroll
                for (int dy = 0; dy < 2; ++dy) {
                    int yi = y0 + dy, ly = ly0 + dy;
                    if ((unsigned)yi >= 128u || (unsigned)ly >= 14u) continue;
                    float wy = dy ? fy : 1.f - fy;
                    #pragma unroll
                    for (int dx = 0; dx < 2; ++dx) {
                        int xi = x0 + dx, lx = lx0 + dx;
                        if ((unsigned)xi >= 128u || (unsigned)lx >= 22u) continue;
                        float w = (dx ? fx : 1.f - fx) * wy * wz;
                        float2* cell = &raw[(lz * 14 + ly) * 22 + lx];
                        atomicAdd(&cell->x, w * val);
                        atomicAdd(&cell->y, w);
                    }
                }
            }
        }
        __syncthreads();

        // z-pass (in place): column (ly,lx), 14 taps -> rows 3..10
        for (int cc = t; cc < 14 * 22; cc += 256) {
            int ly = cc / 22, lx = cc - ly * 22;
            float2 v[14];
            #pragma unroll
            for (int j = 0; j < 14; ++j) v[j] = raw[(j * 14 + ly) * 22 + lx];
            #pragma unroll
            for (int k = 0; k < 8; ++k) {
                float cm1, c0, cp1; coef(Tz + k, cm1, c0, cp1);
                float sx = (v[k].x + v[k + 6].x) + 3.f * (v[k + 1].x + v[k + 5].x)
                         + cm1 * v[k + 2].x + c0 * v[k + 3].x + cp1 * v[k + 4].x;
                float sy = (v[k].y + v[k + 6].y) + 3.f * (v[k + 1].y + v[k + 5].y)
                         + cm1 * v[k + 2].y + c0 * v[k + 3].y + cp1 * v[k + 4].y;
                raw[((k + 3) * 14 + ly) * 22 + lx] = f2(sx * (1.f / 27.f), sy * (1.f / 27.f));
            }
        }
        __syncthreads();

        // y-pass (in place): column (lz,lx), z rows 3..10
        if (t < 8 * 22) {
            int lz = t / 22, lx = t - lz * 22;
            float2 v[14];
            #pragma unroll
            for (int j = 0; j < 14; ++j) v[j] = raw[((lz + 3) * 14 + j) * 22 + lx];
            #pragma unroll
            for (int k = 0; k < 8; ++k) {
                float cm1, c0, cp1; coef(Ty + k, cm1, c0, cp1);
                float sx = (v[k].x + v[k + 6].x) + 3.f * (v[k + 1].x + v[k + 5].x)
                         + cm1 * v[k + 2].x + c0 * v[k + 3].x + cp1 * v[k + 4].x;
                float sy = (v[k].y + v[k + 6].y) + 3.f * (v[k + 1].y + v[k + 5].y)
                         + cm1 * v[k + 2].y + c0 * v[k + 3].y + cp1 * v[k + 4].y;
                raw[((lz + 3) * 14 + (k + 3)) * 22 + lx] = f2(sx * (1.f / 27.f), sy * (1.f / 27.f));
            }
        }
        __syncthreads();

        // x-pass + division: 4 threads per (z,y) row, float4 store
        {
            int row = t >> 2, qx = t & 3;
            int z = row >> 3, y = row & 7;
            const float2* base = &raw[((z + 3) * 14 + (y + 3)) * 22];
            float2 m[10];
            #pragma unroll
            for (int j = 0; j < 10; ++j) m[j] = base[4 * qx + j];
            float4 res;
            float* rp = (float*)&res;
            #pragma unroll
            for (int xi = 0; xi < 4; ++xi) {
                int gx = Tx + 4 * qx + xi;
                float cm1, c0, cp1; coef(gx, cm1, c0, cp1);
                float sx = (m[xi].x + m[xi + 6].x) + 3.f * (m[xi + 1].x + m[xi + 5].x)
                         + cm1 * m[xi + 2].x + c0 * m[xi + 3].x + cp1 * m[xi + 4].x;
                float sy = (m[xi].y + m[xi + 6].y) + 3.f * (m[xi + 1].y + m[xi + 5].y)
                         + cm1 * m[xi + 2].y + c0 * m[xi + 3].y + cp1 * m[xi + 4].y;
                rp[xi] = (sx * (1.f / 27.f)) / (sy * (1.f / 27.f) + 0.001f);
            }
            *(float4*)(ob + ((size_t)z * NVOX + y) * NVOX + qx * 4) = res;
        }
        __syncthreads();   // raw re-zeroed next iteration
    }
}

// ---------------------------------------------------------------------------
extern "C" void kernel_launch(void* const* d_in, const int* in_sizes, int n_in,
                              void* d_out, int out_size, void* d_ws, size_t ws_size,
                              hipStream_t stream)
{
    const float* q    = (const float*)d_in[0];
    const float* qval = (const float*)d_in[1];
    const float* w1   = (const float*)d_in[2];
    const float* b1   = (const float*)d_in[3];
    const float* w2   = (const float*)d_in[4];
    const float* b2   = (const float*)d_in[5];
    const float* w3   = (const float*)d_in[6];
    const float* b3   = (const float*)d_in[7];
    const float* w4   = (const float*)d_in[8];
    const float* b4   = (const float*)d_in[9];
    const float* w5   = (const float*)d_in[10];
    const float* b5   = (const float*)d_in[11];
    float* out = (float*)d_out;

    // ws layout (bytes):
    char* wsb = (char*)d_ws;
    int*    counts  = (int*)(wsb + 0x000000);  // 32768 ints
    int*    nact    = (int*)(wsb + 0x020000);  // 1 int
    int*    part    = (int*)(wsb + 0x020100);  // 128 ints
    int*    partoff = (int*)(wsb + 0x020500);  // 128 ints
    int*    offsets = (int*)(wsb + 0x020900);  // 32769 ints
    int*    active  = (int*)(wsb + 0x041000);  // 32768 ints
    float4* pts     = (float4*)(wsb + 0x061000);   // 30720 float4
    float4* binned  = (float4*)(wsb + 0x0D9000);   // <=245760 float4
    float*  x1g     = (float*)(wsb + 0x500000);    // 30720 floats

    hipMemsetAsync(nact, 0, 4, stream);

    zero_out<<<4096, 256, 0, stream>>>((float4*)out);

    mlp_stage1<<<240, 256, 0, stream>>>(q, w1, b1, x1g);

    mlp_tail<<<NB, 256, 0, stream>>>(x1g, qval, w2, b2, w3, b3,
                                     w4, b4, w5, b5, pts);

    count_bins<<<NB, 256, 0, stream>>>(pts, counts);

    scan_a<<<128, 256, 0, stream>>>(counts, offsets, part);
    scan_b<<<1, 128, 0, stream>>>(part, partoff, offsets);
    scan_c<<<128, 256, 0, stream>>>(offsets, partoff, counts, active, nact);

    bin_fill<<<NB, 256, 0, stream>>>(pts, offsets, binned);

    tile_active<<<1024, 256, 0, stream>>>(binned, offsets, active, nact, out);
}